// Round 2
// baseline (66.947 us; speedup 1.0000x reference)
//
#include <hip/hip_runtime.h>

// Problem constants (from reference): H=64, EH=128, B=512, T=512
#define B_  512
#define T_  512
#define H_  64
#define EH_ 128   // 2*H
#define NW  8     // waves per block (512 threads)

__device__ __forceinline__ float wred_sum(float v) {
#pragma unroll
  for (int off = 32; off; off >>= 1) v += __shfl_xor(v, off, 64);
  return v;
}

__device__ __forceinline__ float sigm(float x) { return 1.0f / (1.0f + __expf(-x)); }

// One pipeline step: consume ecur (16 rows), optionally prefetch into enxt.
// All array indexing static (inlined + unrolled) so everything stays in VGPRs.
__device__ __forceinline__ void attn_step(const float4 (&ecur)[8], float4 (&enxt)[8],
                                          bool doload, const float* __restrict__ base,
                                          int next_row0, const float4& w4, float cb,
                                          float& m, float& l, float4& acc)
{
  if (doload) {
#pragma unroll
    for (int u = 0; u < 8; ++u)
      enxt[u] = *(const float4*)(base + (size_t)(next_row0 + 2 * u) * EH_);
  }
  float s[8];
#pragma unroll
  for (int u = 0; u < 8; ++u) {
    float4 e = ecur[u];
    s[u] = e.x * w4.x + e.y * w4.y + e.z * w4.z + e.w * w4.w;
  }
#pragma unroll
  for (int off = 16; off; off >>= 1)
#pragma unroll
    for (int u = 0; u < 8; ++u)
      s[u] += __shfl_xor(s[u], off, 64);   // stays within each 32-lane half

  float mx = fmaxf(fmaxf(fmaxf(s[0], s[1]), fmaxf(s[2], s[3])),
                   fmaxf(fmaxf(s[4], s[5]), fmaxf(s[6], s[7]))) + cb;
  float mnew  = fmaxf(m, mx);
  float scale = __expf(m - mnew);
  float p[8];
#pragma unroll
  for (int u = 0; u < 8; ++u) p[u] = __expf(s[u] + cb - mnew);
  float ps = 0.f, ax = 0.f, ay = 0.f, az = 0.f, aw = 0.f;
#pragma unroll
  for (int u = 0; u < 8; ++u) {
    ps += p[u];
    ax += p[u] * ecur[u].x; ay += p[u] * ecur[u].y;
    az += p[u] * ecur[u].z; aw += p[u] * ecur[u].w;
  }
  l     = l * scale + ps;
  acc.x = acc.x * scale + ax;
  acc.y = acc.y * scale + ay;
  acc.z = acc.z * scale + az;
  acc.w = acc.w * scale + aw;
  m = mnew;
}

__global__ __launch_bounds__(512, 4)
void attn_decoder_fused(const float* __restrict__ h0, const float* __restrict__ c0,
                        const float* __restrict__ enc,
                        const float* __restrict__ Wa,  const float* __restrict__ ba,
                        const float* __restrict__ Wc,  const float* __restrict__ bc,
                        const float* __restrict__ wif, const float* __restrict__ whf,
                        const float* __restrict__ bif, const float* __restrict__ bhf,
                        const float* __restrict__ wir, const float* __restrict__ whr,
                        const float* __restrict__ bir, const float* __restrict__ bhr,
                        const int* __restrict__ dip,
                        float* __restrict__ out)
{
  const int b    = blockIdx.x;
  const int tid  = threadIdx.x;
  const int lane = tid & 63;
  const int wv   = tid >> 6;    // 0..7
  const int half = lane >> 5;   // 0 or 1 (row parity)
  const int hl   = lane & 31;   // 0..31 (column group)

  __shared__ float s_m[2 * NW], s_l[2 * NW];
  __shared__ float s_acc[2 * NW][EH_];
  __shared__ float s_cat[2 * EH_];      // [enc[b,di,:], attn_applied]
  __shared__ float s_part[4][H_];
  __shared__ float s_comb[H_];
  __shared__ float s_h0[2 * H_];
  __shared__ float s_gates[2][4 * H_];

  const float* encb = enc + (size_t)b * T_ * EH_;

  // cb = dec_hidden[b] . Wa[128:256] + ba  (full 64-lane reduce, one-time)
  float2 dh = *(const float2*)(&h0[b * 2 * H_ + 2 * lane]);
  float2 w2 = *(const float2*)(&Wa[EH_ + 2 * lane]);
  const float cb = wred_sum(dh.x * w2.x + dh.y * w2.y) + ba[0];

  const float4 w4 = *(const float4*)(&Wa[4 * hl]);

  // wave wv owns rows [wv*64, wv*64+64); half 0 = even rows, half 1 = odd rows
  const float* base = encb + (size_t)(wv * 64 + half) * EH_ + 4 * hl;

  float  m = -1e30f, l = 0.0f;
  float4 acc = {0.f, 0.f, 0.f, 0.f};
  float4 e0[8], e1[8];

#pragma unroll
  for (int u = 0; u < 8; ++u)
    e0[u] = *(const float4*)(base + (size_t)(2 * u) * EH_);

  attn_step(e0, e1, true,  base, 16, w4, cb, m, l, acc);  // rows  0..15, prefetch 16..31
  attn_step(e1, e0, true,  base, 32, w4, cb, m, l, acc);  // rows 16..31, prefetch 32..47
  attn_step(e0, e1, true,  base, 48, w4, cb, m, l, acc);  // rows 32..47, prefetch 48..63
  attn_step(e1, e0, false, base, 0,  w4, cb, m, l, acc);  // rows 48..63

  const int wv2 = wv * 2 + half;   // 16 partial states
  *(float4*)(&s_acc[wv2][4 * hl]) = acc;
  if (hl == 0) { s_m[wv2] = m; s_l[wv2] = l; }
  __syncthreads();

  const int di = dip[0];

  // merge 16 partial softmax states; build out_cat in LDS
  if (tid < EH_) {
    float M = s_m[0];
#pragma unroll
    for (int w = 1; w < 2 * NW; ++w) M = fmaxf(M, s_m[w]);
    float L = 0.0f, a = 0.0f;
#pragma unroll
    for (int w = 0; w < 2 * NW; ++w) {
      float ew = __expf(s_m[w] - M);
      L += s_l[w] * ew;
      a += s_acc[w][tid] * ew;
    }
    s_cat[EH_ + tid] = a / L;                        // attn_applied
    s_cat[tid]       = encb[(size_t)di * EH_ + tid]; // enc[b, di, :]
  } else if (tid < 2 * EH_) {
    int j = tid - EH_;                               // 0..127
    s_h0[j] = h0[(j >> 6) * B_ * H_ + b * H_ + (j & 63)];
  }
  __syncthreads();

  // comb = relu(out_cat @ Wc^T + bc) : 64 outputs, 256-dot each, 4-way split
  if (tid < 256) {
    int k = tid & 63, part = tid >> 6;
    const float4* wrow = (const float4*)(Wc + k * 256 + part * 64);
    const float4* cat  = (const float4*)(s_cat + part * 64);
    float a = 0.0f;
#pragma unroll
    for (int j = 0; j < 16; ++j) {
      float4 w = wrow[j], c = cat[j];
      a += w.x * c.x + w.y * c.y + w.z * c.z + w.w * c.w;
    }
    s_part[part][k] = a;
  }
  __syncthreads();
  if (tid < H_) {
    float a = s_part[0][tid] + s_part[1][tid] + s_part[2][tid] + s_part[3][tid] + bc[tid];
    s_comb[tid] = fmaxf(a, 0.0f);
  }
  __syncthreads();

  // gates: 512 threads, one gate each: dir = tid>>8, g = tid&255
  {
    int dir = tid >> 8, g = tid & 255;
    const float* wih = dir ? wir : wif;
    const float* whh = dir ? whr : whf;
    const float* bih = dir ? bir : bif;
    const float* bhh = dir ? bhr : bhf;
    float a = bih[g] + bhh[g];
    const float4* wi = (const float4*)(wih + g * H_);
    const float4* wh = (const float4*)(whh + g * H_);
    const float4* cm = (const float4*)(s_comb);
    const float4* hh = (const float4*)(s_h0 + dir * H_);
#pragma unroll
    for (int j = 0; j < 16; ++j) {
      float4 a1 = wi[j], x1 = cm[j];
      float4 a2 = wh[j], x2 = hh[j];
      a += a1.x * x1.x + a1.y * x1.y + a1.z * x1.z + a1.w * x1.w
         + a2.x * x2.x + a2.y * x2.y + a2.z * x2.z + a2.w * x2.w;
    }
    s_gates[dir][g] = a;
  }
  __syncthreads();

  // finalize LSTM + write all three outputs
  if (tid < 2 * H_) {
    int dir = tid >> 6, j = tid & 63;
    float gi = s_gates[dir][j];
    float gf = s_gates[dir][H_ + j];
    float gg = s_gates[dir][2 * H_ + j];
    float go = s_gates[dir][3 * H_ + j];
    float cp = c0[dir * B_ * H_ + b * H_ + j];
    float cn = sigm(gf) * cp + sigm(gi) * tanhf(gg);
    float hn = sigm(go) * tanhf(cn);
    out[b * 2 * H_ + dir * H_ + j]                    = hn;  // output (b,1,128)
    out[B_ * 2 * H_ + dir * B_ * H_ + b * H_ + j]     = hn;  // h_new (2,b,64)
    out[2 * B_ * 2 * H_ + dir * B_ * H_ + b * H_ + j] = cn;  // c_new (2,b,64)
  }
}

extern "C" void kernel_launch(void* const* d_in, const int* in_sizes, int n_in,
                              void* d_out, int out_size, void* d_ws, size_t ws_size,
                              hipStream_t stream) {
  const float* h0  = (const float*)d_in[0];
  const float* c0  = (const float*)d_in[1];
  const float* enc = (const float*)d_in[2];
  const float* Wa  = (const float*)d_in[3];
  const float* ba  = (const float*)d_in[4];
  const float* Wc  = (const float*)d_in[5];
  const float* bc  = (const float*)d_in[6];
  const float* wif = (const float*)d_in[7];
  const float* whf = (const float*)d_in[8];
  const float* bif = (const float*)d_in[9];
  const float* bhf = (const float*)d_in[10];
  const float* wir = (const float*)d_in[11];
  const float* whr = (const float*)d_in[12];
  const float* bir = (const float*)d_in[13];
  const float* bhr = (const float*)d_in[14];
  const int*   dip = (const int*)d_in[15];
  float* out = (float*)d_out;

  attn_decoder_fused<<<B_, 512, 0, stream>>>(h0, c0, enc, Wa, ba, Wc, bc,
                                             wif, whf, bif, bhf,
                                             wir, whr, bir, bhr, dip, out);
}

// Round 3
// 65.714 us; speedup vs baseline: 1.0188x; 1.0188x over previous
//
#include <hip/hip_runtime.h>

// Problem constants (from reference): H=64, EH=128, B=512, T=512
#define B_  512
#define T_  512
#define H_  64
#define EH_ 128    // 2*H
#define NSPLIT 4   // T split across blocks
#define ROWS (T_ / NSPLIT)   // 128 rows per block
#define WS_STRIDE 132        // floats per partial state: acc[128], m, l, pad

__device__ __forceinline__ float wred_sum(float v) {
#pragma unroll
  for (int off = 32; off; off >>= 1) v += __shfl_xor(v, off, 64);
  return v;
}

__device__ __forceinline__ float sigm(float x) { return 1.0f / (1.0f + __expf(-x)); }

// ---------------- Kernel A: partial online-softmax attention ----------------
// grid = B*NSPLIT blocks of 512 threads. Block (b, sp) processes rows
// [sp*128, sp*128+128) of enc[b], producing one merged partial state
// (acc[128], m, l) in ws.
__global__ __launch_bounds__(512, 8)
void attn_partial(const float* __restrict__ h0, const float* __restrict__ enc,
                  const float* __restrict__ Wa, const float* __restrict__ ba,
                  float* __restrict__ ws)
{
  const int bid  = blockIdx.x;
  const int b    = bid >> 2;
  const int sp   = bid & (NSPLIT - 1);
  const int tid  = threadIdx.x;
  const int lane = tid & 63;
  const int wv   = tid >> 6;   // 0..7

  __shared__ float s_m[8], s_l[8];
  __shared__ float s_acc[8][EH_];

  const float* encb = enc + (size_t)b * T_ * EH_;

  // cb = dec_hidden[b] . Wa[128:256] + ba
  float2 dh = *(const float2*)(&h0[b * 2 * H_ + 2 * lane]);
  float2 w2 = *(const float2*)(&Wa[EH_ + 2 * lane]);
  const float cb = wred_sum(dh.x * w2.x + dh.y * w2.y) + ba[0];

  const float2 w1 = *(const float2*)(&Wa[2 * lane]);

  // wave wv owns rows [sp*128 + wv*16, +16)
  float m = -1e30f, l = 0.0f, accx = 0.0f, accy = 0.0f;
  const int t0 = sp * ROWS + wv * (ROWS / 8);

  for (int t = t0; t < t0 + ROWS / 8; t += 8) {
    float2 e[8];
    float  s[8];
#pragma unroll
    for (int u = 0; u < 8; ++u)
      e[u] = *(const float2*)(&encb[(size_t)(t + u) * EH_ + 2 * lane]);
#pragma unroll
    for (int u = 0; u < 8; ++u)
      s[u] = e[u].x * w1.x + e[u].y * w1.y;
#pragma unroll
    for (int off = 32; off; off >>= 1)
#pragma unroll
      for (int u = 0; u < 8; ++u)
        s[u] += __shfl_xor(s[u], off, 64);

    float mx = cb + fmaxf(fmaxf(fmaxf(s[0], s[1]), fmaxf(s[2], s[3])),
                          fmaxf(fmaxf(s[4], s[5]), fmaxf(s[6], s[7])));
    float mnew  = fmaxf(m, mx);
    float scale = __expf(m - mnew);
    float p[8];
#pragma unroll
    for (int u = 0; u < 8; ++u) p[u] = __expf(s[u] + cb - mnew);
    float ps = 0.0f, ax = 0.0f, ay = 0.0f;
#pragma unroll
    for (int u = 0; u < 8; ++u) { ps += p[u]; ax += p[u] * e[u].x; ay += p[u] * e[u].y; }
    l    = l * scale + ps;
    accx = accx * scale + ax;
    accy = accy * scale + ay;
    m    = mnew;
  }

  s_acc[wv][2 * lane]     = accx;
  s_acc[wv][2 * lane + 1] = accy;
  if (lane == 0) { s_m[wv] = m; s_l[wv] = l; }
  __syncthreads();

  // in-block merge of 8 wave states -> one (acc, m, l); write to ws
  float* wsp = ws + (size_t)bid * WS_STRIDE;
  if (tid < EH_) {
    float M = s_m[0];
#pragma unroll
    for (int w = 1; w < 8; ++w) M = fmaxf(M, s_m[w]);
    float A = 0.0f;
#pragma unroll
    for (int w = 0; w < 8; ++w) A += s_acc[w][tid] * __expf(s_m[w] - M);
    wsp[tid] = A;
    if (tid == 0) {
      float L = 0.0f;
#pragma unroll
      for (int w = 0; w < 8; ++w) L += s_l[w] * __expf(s_m[w] - M);
      wsp[EH_]     = M;
      wsp[EH_ + 1] = L;
    }
  }
}

// ---------------- Kernel B: merge partials + comb + LSTM epilogue ----------------
// grid = B blocks of 256 threads.
__global__ __launch_bounds__(256, 4)
void attn_epilogue(const float* __restrict__ h0, const float* __restrict__ c0,
                   const float* __restrict__ enc,
                   const float* __restrict__ Wc,  const float* __restrict__ bc,
                   const float* __restrict__ wif, const float* __restrict__ whf,
                   const float* __restrict__ bif, const float* __restrict__ bhf,
                   const float* __restrict__ wir, const float* __restrict__ whr,
                   const float* __restrict__ bir, const float* __restrict__ bhr,
                   const int* __restrict__ dip,
                   const float* __restrict__ ws,
                   float* __restrict__ out)
{
  const int b   = blockIdx.x;
  const int tid = threadIdx.x;

  __shared__ float s_cat[2 * EH_];
  __shared__ float s_part[4][H_];
  __shared__ float s_comb[H_];
  __shared__ float s_h0[2 * H_];
  __shared__ float s_gates[2][4 * H_];

  const int di = dip[0];
  const float* wsb = ws + (size_t)b * NSPLIT * WS_STRIDE;

  if (tid < EH_) {
    // merge NSPLIT partial states
    float M = wsb[EH_];
#pragma unroll
    for (int s = 1; s < NSPLIT; ++s) M = fmaxf(M, wsb[s * WS_STRIDE + EH_]);
    float L = 0.0f, A = 0.0f;
#pragma unroll
    for (int s = 0; s < NSPLIT; ++s) {
      float ew = __expf(wsb[s * WS_STRIDE + EH_] - M);
      L += wsb[s * WS_STRIDE + EH_ + 1] * ew;
      A += wsb[s * WS_STRIDE + tid] * ew;
    }
    s_cat[EH_ + tid] = A / L;                                       // attn_applied
    s_cat[tid]       = enc[((size_t)b * T_ + di) * EH_ + tid];      // enc[b,di,:]
  } else {
    int j = tid - EH_;   // 0..127
    s_h0[j] = h0[(j >> 6) * B_ * H_ + b * H_ + (j & 63)];
  }
  __syncthreads();

  // comb = relu(cat @ Wc^T + bc): 64 outputs, 256-dot, 4-way split across 256 threads
  {
    int k = tid & 63, part = tid >> 6;
    const float4* wrow = (const float4*)(Wc + k * 256 + part * 64);
    const float4* cat  = (const float4*)(s_cat + part * 64);
    float a = 0.0f;
#pragma unroll
    for (int j = 0; j < 16; ++j) {
      float4 w = wrow[j], c = cat[j];
      a += w.x * c.x + w.y * c.y + w.z * c.z + w.w * c.w;
    }
    s_part[part][k] = a;
  }
  __syncthreads();
  if (tid < H_) {
    float a = s_part[0][tid] + s_part[1][tid] + s_part[2][tid] + s_part[3][tid] + bc[tid];
    s_comb[tid] = fmaxf(a, 0.0f);
  }
  __syncthreads();

  // gates: each thread computes gate g=tid for both directions
  {
    int g = tid;  // 0..255
#pragma unroll
    for (int dir = 0; dir < 2; ++dir) {
      const float* wih = dir ? wir : wif;
      const float* whh = dir ? whr : whf;
      const float* bih = dir ? bir : bif;
      const float* bhh = dir ? bhr : bhf;
      float a = bih[g] + bhh[g];
      const float4* wi = (const float4*)(wih + g * H_);
      const float4* wh = (const float4*)(whh + g * H_);
      const float4* cm = (const float4*)(s_comb);
      const float4* hh = (const float4*)(s_h0 + dir * H_);
#pragma unroll
      for (int j = 0; j < 16; ++j) {
        float4 a1 = wi[j], x1 = cm[j];
        float4 a2 = wh[j], x2 = hh[j];
        a += a1.x * x1.x + a1.y * x1.y + a1.z * x1.z + a1.w * x1.w
           + a2.x * x2.x + a2.y * x2.y + a2.z * x2.z + a2.w * x2.w;
      }
      s_gates[dir][g] = a;
    }
  }
  __syncthreads();

  if (tid < 2 * H_) {
    int dir = tid >> 6, j = tid & 63;
    float gi = s_gates[dir][j];
    float gf = s_gates[dir][H_ + j];
    float gg = s_gates[dir][2 * H_ + j];
    float go = s_gates[dir][3 * H_ + j];
    float cp = c0[dir * B_ * H_ + b * H_ + j];
    float cn = sigm(gf) * cp + sigm(gi) * tanhf(gg);
    float hn = sigm(go) * tanhf(cn);
    out[b * 2 * H_ + dir * H_ + j]                    = hn;  // output (b,1,128)
    out[B_ * 2 * H_ + dir * B_ * H_ + b * H_ + j]     = hn;  // h_new (2,b,64)
    out[2 * B_ * 2 * H_ + dir * B_ * H_ + b * H_ + j] = cn;  // c_new (2,b,64)
  }
}

extern "C" void kernel_launch(void* const* d_in, const int* in_sizes, int n_in,
                              void* d_out, int out_size, void* d_ws, size_t ws_size,
                              hipStream_t stream) {
  const float* h0  = (const float*)d_in[0];
  const float* c0  = (const float*)d_in[1];
  const float* enc = (const float*)d_in[2];
  const float* Wa  = (const float*)d_in[3];
  const float* ba  = (const float*)d_in[4];
  const float* Wc  = (const float*)d_in[5];
  const float* bc  = (const float*)d_in[6];
  const float* wif = (const float*)d_in[7];
  const float* whf = (const float*)d_in[8];
  const float* bif = (const float*)d_in[9];
  const float* bhf = (const float*)d_in[10];
  const float* wir = (const float*)d_in[11];
  const float* whr = (const float*)d_in[12];
  const float* bir = (const float*)d_in[13];
  const float* bhr = (const float*)d_in[14];
  const int*   dip = (const int*)d_in[15];
  float* out = (float*)d_out;
  float* ws  = (float*)d_ws;

  attn_partial<<<B_ * NSPLIT, 512, 0, stream>>>(h0, enc, Wa, ba, ws);
  attn_epilogue<<<B_, 256, 0, stream>>>(h0, c0, enc, Wc, bc,
                                        wif, whf, bif, bhf,
                                        wir, whr, bir, bhr, dip, ws, out);
}

// Round 4
// 46.669 us; speedup vs baseline: 1.4345x; 1.4081x over previous
//
#include <hip/hip_runtime.h>

// Problem constants (from reference): H=64, EH=128, B=512, T=512
#define B_  512
#define T_  512
#define H_  64
#define EH_ 128   // 2*H
#define NW  8     // waves per block (512 threads)
#define NG  32    // partial-softmax groups per block (NW * 4)

__device__ __forceinline__ float wred_sum(float v) {
#pragma unroll
  for (int off = 32; off; off >>= 1) v += __shfl_xor(v, off, 64);
  return v;
}

__device__ __forceinline__ float sigm(float x) { return 1.0f / (1.0f + __expf(-x)); }

__device__ __forceinline__ float dot8(const float4& a1, const float4& a2,
                                      const float4& b1, const float4& b2) {
  return a1.x * b1.x + a1.y * b1.y + a1.z * b1.z + a1.w * b1.w
       + a2.x * b2.x + a2.y * b2.y + a2.z * b2.z + a2.w * b2.w;
}

__global__ __launch_bounds__(512, 4)
void attn_decoder_fused(const float* __restrict__ h0, const float* __restrict__ c0,
                        const float* __restrict__ enc,
                        const float* __restrict__ Wa,  const float* __restrict__ ba,
                        const float* __restrict__ Wc,  const float* __restrict__ bc,
                        const float* __restrict__ wif, const float* __restrict__ whf,
                        const float* __restrict__ bif, const float* __restrict__ bhf,
                        const float* __restrict__ wir, const float* __restrict__ whr,
                        const float* __restrict__ bir, const float* __restrict__ bhr,
                        const int* __restrict__ dip,
                        float* __restrict__ out)
{
  const int b    = blockIdx.x;
  const int tid  = threadIdx.x;
  const int lane = tid & 63;
  const int wv   = tid >> 6;    // 0..7
  const int grp  = lane >> 4;   // 0..3  (row within quad)
  const int gl   = lane & 15;   // 0..15 (column group: 16 lanes per row)

  __shared__ float s_m[NG], s_l[NG];
  __shared__ float s_acc[NG][EH_];      // 16 KB
  __shared__ float s_cat[2 * EH_];      // [enc[b,di,:], attn_applied]
  __shared__ float s_part[4][H_];
  __shared__ float s_comb[H_];
  __shared__ float s_h0[2 * H_];
  __shared__ float s_gates[2][4 * H_];

  const float* encb = enc + (size_t)b * T_ * EH_;

  // cb = dec_hidden[b] . Wa[128:256] + ba  (one-time full-wave reduce)
  float2 dh = *(const float2*)(&h0[b * 2 * H_ + 2 * lane]);
  float2 wz = *(const float2*)(&Wa[EH_ + 2 * lane]);
  const float cb = wred_sum(dh.x * wz.x + dh.y * wz.y) + ba[0];

  // each lane's 8 attention-weight columns
  const float4 w1 = *(const float4*)(&Wa[4 * gl]);
  const float4 w2 = *(const float4*)(&Wa[64 + 4 * gl]);

  // wave wv owns rows [wv*64, wv*64+64); group grp handles rows grp, grp+4, ... (mod 16)
  float  m = -1e30f, l = 0.0f;
  float4 acc1 = {0.f, 0.f, 0.f, 0.f}, acc2 = {0.f, 0.f, 0.f, 0.f};

  const float* rb = encb + (size_t)(wv * 64 + grp) * EH_;

#pragma unroll 1
  for (int it = 0; it < 4; ++it) {
    const float* p0 = rb + (size_t)(it * 16) * EH_;
    // 8 loads issued up front: 4 rows (grp, grp+4, grp+8, grp+12), 2 halves each
    float4 eA1 = *(const float4*)(p0 + 4 * gl);
    float4 eA2 = *(const float4*)(p0 + 64 + 4 * gl);
    float4 eB1 = *(const float4*)(p0 + 4 * EH_ + 4 * gl);
    float4 eB2 = *(const float4*)(p0 + 4 * EH_ + 64 + 4 * gl);
    float4 eC1 = *(const float4*)(p0 + 8 * EH_ + 4 * gl);
    float4 eC2 = *(const float4*)(p0 + 8 * EH_ + 64 + 4 * gl);
    float4 eD1 = *(const float4*)(p0 + 12 * EH_ + 4 * gl);
    float4 eD2 = *(const float4*)(p0 + 12 * EH_ + 64 + 4 * gl);

    float sA = dot8(eA1, eA2, w1, w2);
    float sB = dot8(eB1, eB2, w1, w2);
    float sC = dot8(eC1, eC2, w1, w2);
    float sD = dot8(eD1, eD2, w1, w2);

    // 4-stage butterfly within each 16-lane group; 4 rows reduced per stage op
#pragma unroll
    for (int off = 8; off; off >>= 1) {
      sA += __shfl_xor(sA, off, 64);
      sB += __shfl_xor(sB, off, 64);
      sC += __shfl_xor(sC, off, 64);
      sD += __shfl_xor(sD, off, 64);
    }

    float mx    = fmaxf(fmaxf(sA, sB), fmaxf(sC, sD)) + cb;
    float mnew  = fmaxf(m, mx);
    float scale = __expf(m - mnew);
    float pA = __expf(sA + cb - mnew);
    float pB = __expf(sB + cb - mnew);
    float pC = __expf(sC + cb - mnew);
    float pD = __expf(sD + cb - mnew);
    l = l * scale + (pA + pB + pC + pD);
    acc1.x = acc1.x * scale + pA * eA1.x + pB * eB1.x + pC * eC1.x + pD * eD1.x;
    acc1.y = acc1.y * scale + pA * eA1.y + pB * eB1.y + pC * eC1.y + pD * eD1.y;
    acc1.z = acc1.z * scale + pA * eA1.z + pB * eB1.z + pC * eC1.z + pD * eD1.z;
    acc1.w = acc1.w * scale + pA * eA1.w + pB * eB1.w + pC * eC1.w + pD * eD1.w;
    acc2.x = acc2.x * scale + pA * eA2.x + pB * eB2.x + pC * eC2.x + pD * eD2.x;
    acc2.y = acc2.y * scale + pA * eA2.y + pB * eB2.y + pC * eC2.y + pD * eD2.y;
    acc2.z = acc2.z * scale + pA * eA2.z + pB * eB2.z + pC * eC2.z + pD * eD2.z;
    acc2.w = acc2.w * scale + pA * eA2.w + pB * eB2.w + pC * eC2.w + pD * eD2.w;
    m = mnew;
  }

  // stash group-partial state: group g covered rows {wv*64 + grp + 4k + 16it}
  const int g = wv * 4 + grp;   // 0..31
  *(float4*)(&s_acc[g][4 * gl])      = acc1;
  *(float4*)(&s_acc[g][64 + 4 * gl]) = acc2;
  if (gl == 0) { s_m[g] = m; s_l[g] = l; }
  __syncthreads();

  const int di = dip[0];

  // merge 32 partial softmax states; build out_cat in LDS
  if (tid < EH_) {
    float M = s_m[0];
#pragma unroll
    for (int w = 1; w < NG; ++w) M = fmaxf(M, s_m[w]);
    float L = 0.0f, a = 0.0f;
#pragma unroll
    for (int w = 0; w < NG; ++w) {
      float ew = __expf(s_m[w] - M);
      L += s_l[w] * ew;
      a += s_acc[w][tid] * ew;
    }
    s_cat[EH_ + tid] = a / L;                        // attn_applied
    s_cat[tid]       = encb[(size_t)di * EH_ + tid]; // enc[b, di, :]
  } else if (tid < 2 * EH_) {
    int j = tid - EH_;                               // 0..127
    s_h0[j] = h0[(j >> 6) * B_ * H_ + b * H_ + (j & 63)];
  }
  __syncthreads();

  // comb = relu(out_cat @ Wc^T + bc) : 64 outputs, 256-dot each, 4-way split
  if (tid < 256) {
    int k = tid & 63, part = tid >> 6;
    const float4* wrow = (const float4*)(Wc + k * 256 + part * 64);
    const float4* cat  = (const float4*)(s_cat + part * 64);
    float a = 0.0f;
#pragma unroll
    for (int j = 0; j < 16; ++j) {
      float4 w = wrow[j], c = cat[j];
      a += w.x * c.x + w.y * c.y + w.z * c.z + w.w * c.w;
    }
    s_part[part][k] = a;
  }
  __syncthreads();
  if (tid < H_) {
    float a = s_part[0][tid] + s_part[1][tid] + s_part[2][tid] + s_part[3][tid] + bc[tid];
    s_comb[tid] = fmaxf(a, 0.0f);
  }
  __syncthreads();

  // gates: 512 threads, one gate each: dir = tid>>8, g = tid&255
  {
    int dir = tid >> 8, gg = tid & 255;
    const float* wih = dir ? wir : wif;
    const float* whh = dir ? whr : whf;
    const float* bih = dir ? bir : bif;
    const float* bhh = dir ? bhr : bhf;
    float a = bih[gg] + bhh[gg];
    const float4* wi = (const float4*)(wih + gg * H_);
    const float4* wh = (const float4*)(whh + gg * H_);
    const float4* cm = (const float4*)(s_comb);
    const float4* hh = (const float4*)(s_h0 + dir * H_);
#pragma unroll
    for (int j = 0; j < 16; ++j) {
      float4 a1 = wi[j], x1 = cm[j];
      float4 a2 = wh[j], x2 = hh[j];
      a += a1.x * x1.x + a1.y * x1.y + a1.z * x1.z + a1.w * x1.w
         + a2.x * x2.x + a2.y * x2.y + a2.z * x2.z + a2.w * x2.w;
    }
    s_gates[dir][gg] = a;
  }
  __syncthreads();

  // finalize LSTM + write all three outputs
  if (tid < 2 * H_) {
    int dir = tid >> 6, j = tid & 63;
    float gi = s_gates[dir][j];
    float gf = s_gates[dir][H_ + j];
    float gg = s_gates[dir][2 * H_ + j];
    float go = s_gates[dir][3 * H_ + j];
    float cp = c0[dir * B_ * H_ + b * H_ + j];
    float cn = sigm(gf) * cp + sigm(gi) * tanhf(gg);
    float hn = sigm(go) * tanhf(cn);
    out[b * 2 * H_ + dir * H_ + j]                    = hn;  // output (b,1,128)
    out[B_ * 2 * H_ + dir * B_ * H_ + b * H_ + j]     = hn;  // h_new (2,b,64)
    out[2 * B_ * 2 * H_ + dir * B_ * H_ + b * H_ + j] = cn;  // c_new (2,b,64)
  }
}

extern "C" void kernel_launch(void* const* d_in, const int* in_sizes, int n_in,
                              void* d_out, int out_size, void* d_ws, size_t ws_size,
                              hipStream_t stream) {
  const float* h0  = (const float*)d_in[0];
  const float* c0  = (const float*)d_in[1];
  const float* enc = (const float*)d_in[2];
  const float* Wa  = (const float*)d_in[3];
  const float* ba  = (const float*)d_in[4];
  const float* Wc  = (const float*)d_in[5];
  const float* bc  = (const float*)d_in[6];
  const float* wif = (const float*)d_in[7];
  const float* whf = (const float*)d_in[8];
  const float* bif = (const float*)d_in[9];
  const float* bhf = (const float*)d_in[10];
  const float* wir = (const float*)d_in[11];
  const float* whr = (const float*)d_in[12];
  const float* bir = (const float*)d_in[13];
  const float* bhr = (const float*)d_in[14];
  const int*   dip = (const int*)d_in[15];
  float* out = (float*)d_out;

  attn_decoder_fused<<<B_, 512, 0, stream>>>(h0, c0, enc, Wa, ba, Wc, bc,
                                             wif, whf, bif, bhf,
                                             wir, whr, bir, bhr, dip, out);
}